// Round 3
// baseline (240.595 us; speedup 1.0000x reference)
//
#include <hip/hip_runtime.h>
#include <stdint.h>

// DETR PartMap: [2, B, Q, H, W] outside-box masks (1.0 outside, 0.0 inside).
// B=64, Q=300, H=W=40. Output 61.44M fp32 = 245.8 MB -> pure write-BW problem.
//
// Fused single kernel, wave-per-entry: each 64-lane wave owns EPW=4 consecutive
// (s,b,q) boxes (= 4*400 float4 = 25.6 KB contiguous output). Lanes 0..3
// compute the 4 box masks in-register (40-bit x-outside bitmask + y1/y2),
// broadcast via v_readlane; per-lane (h, shift) tables for the 7 row-chunks
// are computed once per wave and reused across entries. Inner loop ~16 VALU
// insts per float4, no per-f4 loads, fully coalesced dwordx4 stores.

#define B_   64
#define Q_   300
#define HM   40
#define WM   40
#define NBOX 38400            // 2*B*Q
#define EPW  4                // entries per wave
// waves = NBOX/EPW = 9600; block = 256 (4 waves) -> 2400 blocks

__global__ __launch_bounds__(256) void partmap_fused(
    const float* __restrict__ obj,
    const float* __restrict__ sub,
    const int*   __restrict__ img,     // [B,2] = (h, w) int32
    float4*      __restrict__ out)     // [2,B,Q,H,W] as float4 rows of 10
{
    #pragma clang fp contract(off)
    const int tid  = threadIdx.x;
    const int lane = tid & 63;
    const int wid  = (blockIdx.x << 2) | (tid >> 6);   // global wave id < 9600
    const int e0   = wid * EPW;                        // first entry id

    // ---- per-lane row tables, computed once, reused for all 4 entries ----
    // iteration j covers float4 positions p = j*64 + lane of the 400 per entry
    int h_j[7], sh_j[7];
    #pragma unroll
    for (int j = 0; j < 7; ++j) {
        int p  = j * 64 + lane;        // < 448; only p<400 stored (j==6 masked)
        int h  = p / 10;               // row in [0,40) for valid p
        int w4 = p - 10 * h;           // float4 within row
        h_j[j]  = h;
        sh_j[j] = w4 * 4;              // bit shift into the 40-bit x-mask
    }

    // ---- box compute: all lanes compute entry e0 + (lane&3); lanes 0..3 are
    //      the authoritative copies read back via v_readlane ----
    int id = e0 + (lane & 3);          // (s*64 + b)*300 + q
    int q  = id % Q_;
    int sb = id / Q_;
    int b  = sb & 63;
    int s  = sb >> 6;

    const float* coord = s ? sub : obj;
    float4 c = ((const float4*)coord)[b * Q_ + q];   // (cx, cy, w, h)

    float shh = (float)img[b * 2 + 0];
    float sww = (float)img[b * 2 + 1];

    // Exact numpy op order (no FMA contraction): (cx - 0.5*w) * s / 32, floor.
    float x1f = (c.x - 0.5f * c.z) * sww / 32.0f;
    float y1f = (c.y - 0.5f * c.w) * shh / 32.0f;
    float x2f = (c.x + 0.5f * c.z) * sww / 32.0f;
    float y2f = (c.y + 0.5f * c.w) * shh / 32.0f;

    int x1 = (int)floorf(x1f);                    // >= -20, <= 39
    int y1 = (int)floorf(y1f);
    int x2 = min((int)floorf(x2f), WM - 1);       // in [0,39]
    int y2 = min((int)floorf(y2f), HM - 1);       // in [0,39]

    // 40-bit x-outside mask: bit x set iff (x < x1 || x > x2)
    uint64_t blo = (x1 <= 0) ? ~0ull : ~((1ull << x1) - 1ull);
    uint64_t bhi = (1ull << (x2 + 1)) - 1ull;
    uint64_t outside = (~(blo & bhi)) & ((1ull << 40) - 1ull);
    uint32_t d0 = (uint32_t)outside;
    uint32_t d1 = (uint32_t)(outside >> 32);

    // ---- stream 4 entries: 25.6 KB contiguous, coalesced dwordx4 stores ----
    float4* bp = out + (size_t)e0 * 400 + lane;

    #pragma unroll
    for (int e = 0; e < EPW; ++e) {
        uint32_t sd0 = (uint32_t)__builtin_amdgcn_readlane((int)d0, e);
        uint32_t sd1 = (uint32_t)__builtin_amdgcn_readlane((int)d1, e);
        int      sy1 = __builtin_amdgcn_readlane(y1, e);
        int      sy2 = __builtin_amdgcn_readlane(y2, e);
        uint64_t m64 = ((uint64_t)sd1 << 32) | (uint64_t)sd0;
        float4*  ep  = bp + e * 400;

        #pragma unroll
        for (int j = 0; j < 7; ++j) {
            // all-ones if row h outside [y1,y2]
            int rneg = ((h_j[j] - sy1) | (sy2 - h_j[j])) >> 31;
            uint32_t m = (uint32_t)(m64 >> sh_j[j]) | (uint32_t)rneg;
            float4 r;
            r.x = (float)( m        & 1u);
            r.y = (float)((m >> 1u) & 1u);
            r.z = (float)((m >> 2u) & 1u);
            r.w = (float)((m >> 3u) & 1u);
            if (j < 6 || lane < 16)           // tail: only 400 f4 per entry
                ep[j * 64] = r;
        }
    }
}

extern "C" void kernel_launch(void* const* d_in, const int* in_sizes, int n_in,
                              void* d_out, int out_size, void* d_ws, size_t ws_size,
                              hipStream_t stream) {
    const float* obj = (const float*)d_in[0];   // [B,Q,4] f32
    const float* sub = (const float*)d_in[1];   // [B,Q,4] f32
    const int*   img = (const int*)d_in[2];     // [B,2] int32 (h, w)
    // d_in[3] = mask (bool) — only its shape is used; ignored.

    float4* out = (float4*)d_out;               // [2,B,Q,H,W] f32

    partmap_fused<<<dim3(NBOX / (EPW * 4)), dim3(256), 0, stream>>>(obj, sub, img, out);
}